// Round 10
// baseline (263.923 us; speedup 1.0000x reference)
//
#include <hip/hip_runtime.h>

#define FILLV (-10000.0f)

typedef __attribute__((ext_vector_type(4))) float f32x4;

__device__ __forceinline__ f32x4 vmax4(f32x4 a, f32x4 b) {
    f32x4 r;
    r.x = fmaxf(a.x, b.x);
    r.y = fmaxf(a.y, b.y);
    r.z = fmaxf(a.z, b.z);
    r.w = fmaxf(a.w, b.w);
    return r;
}

__device__ __forceinline__ f32x4 ntload(const f32x4* p) {
    return __builtin_nontemporal_load(p);
}

__device__ __forceinline__ f32x4 fillv4() {
    f32x4 v = {FILLV, FILLV, FILLV, FILLV};
    return v;
}

// ---------------------------------------------------------------------------
// Fused kernel. Blocks [0,G): exact-balanced streaming over the global
// valid-row list (effective split size Ge = min(G, W) so every block < Ge has
// a non-empty range -> writer count per batch is exactly jhi-jlo+1).
// After writing partial slot (b, j): threadfence + atomicAdd(counter[b]).
// The block completing the count reduces b's slots and writes out[b].
// Blocks [G, G+B): write zeros for len<=0 batches.
// counters are zeroed each call by hipMemsetAsync (no cross-call state).
// ---------------------------------------------------------------------------
__global__ __launch_bounds__(256, 4)
void feasel_fused_kernel(const float* __restrict__ feat,
                         const int* __restrict__ lengths,
                         float* __restrict__ part,
                         int* __restrict__ counters,
                         float* __restrict__ out,
                         int B, int L, int DV, int G) {
    const int t  = threadIdx.x;
    const int j  = blockIdx.x;

    if (j >= G) {                        // zero-writer for batch j-G
        const int b = j - G;
        if (lengths[b] <= 0) {
            f32x4 z = {0.f, 0.f, 0.f, 0.f};
            reinterpret_cast<f32x4*>(out)[(size_t)b * DV + t] = z;
        }
        return;
    }

    __shared__ int rowstart[1025];       // B <= 1024
    __shared__ int slotbase[1025];
    __shared__ int isLastSh;

    if (t == 0) {
        rowstart[0] = 0;
        for (int b = 0; b < B; ++b) {
            int len = lengths[b];
            len = len < 0 ? 0 : (len > L ? L : len);
            rowstart[b + 1] = rowstart[b] + len;
        }
    }
    __syncthreads();
    const int W = rowstart[B];
    if (W == 0) return;                  // all outputs handled by zero-writers
    const int Ge = W < G ? W : G;        // effective split: all blocks < Ge non-empty
    if (j >= Ge) return;

    for (int b = t; b < B; b += blockDim.x) {
        int s = 0;
        if (rowstart[b + 1] > rowstart[b]) {
            int jlo = (int)((unsigned long long)rowstart[b] * Ge / W);
            int jhi = (int)((unsigned long long)(rowstart[b + 1] - 1) * Ge / W);
            s = jhi - jlo + 1;
        }
        slotbase[b + 1] = s;
    }
    __syncthreads();
    if (t == 0) {
        slotbase[0] = 0;
        for (int b = 0; b < B; ++b) slotbase[b + 1] += slotbase[b];
    }
    __syncthreads();

    const int r0 = (int)(((unsigned long long)W * j + Ge - 1) / Ge);
    int       r1 = (int)(((unsigned long long)W * (j + 1) + Ge - 1) / Ge);
    if (r1 > W) r1 = W;
    if (r0 >= r1) return;                // cannot happen for j < Ge; safety

    // containing batch for r0
    int lo = 0, hi = B;
    while (hi - lo > 1) {
        int m = (lo + hi) >> 1;
        if (rowstart[m] <= r0) lo = m; else hi = m;
    }
    int b = lo;
    int r = r0;

    while (r < r1) {
        while (rowstart[b + 1] <= r) ++b;
        const int rend  = min(r1, rowstart[b + 1]);
        const int nrows = rend - r;
        const int l     = r - rowstart[b];

        const f32x4* __restrict__ p =
            reinterpret_cast<const f32x4*>(feat) + ((size_t)b * L + l) * DV + t;

        f32x4 a0 = fillv4(), a1 = fillv4(), a2 = fillv4(), a3 = fillv4();
        f32x4 a4 = fillv4(), a5 = fillv4(), a6 = fillv4(), a7 = fillv4();

        int k = 0;
        for (; k + 16 <= nrows; k += 16) {
            f32x4 v0  = ntload(p +  0 * (size_t)DV);
            f32x4 v1  = ntload(p +  1 * (size_t)DV);
            f32x4 v2  = ntload(p +  2 * (size_t)DV);
            f32x4 v3  = ntload(p +  3 * (size_t)DV);
            f32x4 v4  = ntload(p +  4 * (size_t)DV);
            f32x4 v5  = ntload(p +  5 * (size_t)DV);
            f32x4 v6  = ntload(p +  6 * (size_t)DV);
            f32x4 v7  = ntload(p +  7 * (size_t)DV);
            f32x4 v8  = ntload(p +  8 * (size_t)DV);
            f32x4 v9  = ntload(p +  9 * (size_t)DV);
            f32x4 v10 = ntload(p + 10 * (size_t)DV);
            f32x4 v11 = ntload(p + 11 * (size_t)DV);
            f32x4 v12 = ntload(p + 12 * (size_t)DV);
            f32x4 v13 = ntload(p + 13 * (size_t)DV);
            f32x4 v14 = ntload(p + 14 * (size_t)DV);
            f32x4 v15 = ntload(p + 15 * (size_t)DV);
            a0 = vmax4(a0, vmax4(v0,  v8));
            a1 = vmax4(a1, vmax4(v1,  v9));
            a2 = vmax4(a2, vmax4(v2,  v10));
            a3 = vmax4(a3, vmax4(v3,  v11));
            a4 = vmax4(a4, vmax4(v4,  v12));
            a5 = vmax4(a5, vmax4(v5,  v13));
            a6 = vmax4(a6, vmax4(v6,  v14));
            a7 = vmax4(a7, vmax4(v7,  v15));
            p += 16 * (size_t)DV;
        }
        for (; k + 4 <= nrows; k += 4) {
            a0 = vmax4(a0, ntload(p + 0 * (size_t)DV));
            a1 = vmax4(a1, ntload(p + 1 * (size_t)DV));
            a2 = vmax4(a2, ntload(p + 2 * (size_t)DV));
            a3 = vmax4(a3, ntload(p + 3 * (size_t)DV));
            p += 4 * (size_t)DV;
        }
        for (; k < nrows; ++k) {
            a0 = vmax4(a0, ntload(p));
            p += DV;
        }
        a0 = vmax4(a0, a1);
        a2 = vmax4(a2, a3);
        a4 = vmax4(a4, a5);
        a6 = vmax4(a6, a7);
        a0 = vmax4(vmax4(a0, a2), vmax4(a4, a6));

        const int jlo = (int)((unsigned long long)rowstart[b] * Ge / W);
        const int jhi = (int)((unsigned long long)(rowstart[b + 1] - 1) * Ge / W);
        const int sb  = slotbase[b];

        reinterpret_cast<f32x4*>(part)[(size_t)(sb + (j - jlo)) * DV + t] = a0;
        __threadfence();                 // release partial before counting
        if (t == 0) {
            const int target = jhi - jlo + 1;
            const int old    = atomicAdd(&counters[b], 1);
            isLastSh = (old == target - 1) ? 1 : 0;
        }
        __syncthreads();
        if (isLastSh) {
            __threadfence();             // acquire all writers' partials
            f32x4 acc = fillv4();
            for (int jj = jlo; jj <= jhi; ++jj)
                acc = vmax4(acc,
                    reinterpret_cast<const f32x4*>(part)[(size_t)(sb + (jj - jlo)) * DV + t]);
            reinterpret_cast<f32x4*>(out)[(size_t)b * DV + t] = acc;
        }
        __syncthreads();                 // protect isLastSh before next batch

        r = rend;
    }
}

// ---------------------------------------------------------------------------
// Fallback (tiny ws or B > 1024): one block per batch, direct reduction.
// ---------------------------------------------------------------------------
__global__ void feasel_direct_kernel(const float* __restrict__ feat,
                                     const int* __restrict__ lengths,
                                     float* __restrict__ out,
                                     int L, int DV) {
    const int b = blockIdx.x;
    const int t = threadIdx.x;
    int len = lengths[b];
    len = len < 0 ? 0 : (len > L ? L : len);

    const f32x4* __restrict__ p =
        reinterpret_cast<const f32x4*>(feat) + (size_t)b * L * DV + t;

    f32x4 a0 = fillv4(), a1 = fillv4(), a2 = fillv4(), a3 = fillv4();
    int l = 0;
    for (; l + 4 <= len; l += 4) {
        a0 = vmax4(a0, ntload(p + 0 * (size_t)DV));
        a1 = vmax4(a1, ntload(p + 1 * (size_t)DV));
        a2 = vmax4(a2, ntload(p + 2 * (size_t)DV));
        a3 = vmax4(a3, ntload(p + 3 * (size_t)DV));
        p += 4 * (size_t)DV;
    }
    for (; l < len; ++l) {
        a0 = vmax4(a0, ntload(p));
        p += DV;
    }
    a0 = vmax4(vmax4(a0, a1), vmax4(a2, a3));
    if (len <= 0) {
        f32x4 z = {0.f, 0.f, 0.f, 0.f};
        a0 = z;
    }
    reinterpret_cast<f32x4*>(out)[(size_t)b * DV + t] = a0;
}

extern "C" void kernel_launch(void* const* d_in, const int* in_sizes, int n_in,
                              void* d_out, int out_size, void* d_ws, size_t ws_size,
                              hipStream_t stream) {
    const float* feat    = (const float*)d_in[0];   // [B, L, D] fp32
    const int*   lengths = (const int*)d_in[1];     // [B] int32
    float*       out     = (float*)d_out;           // [B, D] fp32

    const int B  = in_sizes[1];
    const int D  = out_size / B;                    // 1024
    const int DV = D / 4;                           // 256 float4 per row
    const int L  = in_sizes[0] / (B * D);           // 4096
    const int G  = 1024;                            // streaming blocks

    const size_t part_bytes = (size_t)(G + B) * D * sizeof(float);
    const size_t need       = part_bytes + (size_t)B * sizeof(int);

    if (need <= ws_size && B <= 1024 && DV <= 256) {
        float* part     = (float*)d_ws;
        int*   counters = (int*)((char*)d_ws + part_bytes);

        hipMemsetAsync(counters, 0, (size_t)B * sizeof(int), stream);

        feasel_fused_kernel<<<G + B, DV, 0, stream>>>(feat, lengths, part,
                                                      counters, out,
                                                      B, L, DV, G);
    } else {
        feasel_direct_kernel<<<B, DV, 0, stream>>>(feat, lengths, out, L, DV);
    }
}

// Round 11
// 99.765 us; speedup vs baseline: 2.6454x; 2.6454x over previous
//
#include <hip/hip_runtime.h>

#define FILLV (-10000.0f)

typedef __attribute__((ext_vector_type(4))) float f32x4;

__device__ __forceinline__ f32x4 vmax4(f32x4 a, f32x4 b) {
    f32x4 r;
    r.x = fmaxf(a.x, b.x);
    r.y = fmaxf(a.y, b.y);
    r.z = fmaxf(a.z, b.z);
    r.w = fmaxf(a.w, b.w);
    return r;
}

__device__ __forceinline__ f32x4 ntload(const f32x4* p) {
    return __builtin_nontemporal_load(p);
}

__device__ __forceinline__ f32x4 fillv4() {
    f32x4 v = {FILLV, FILLV, FILLV, FILLV};
    return v;
}

// Shared helpers: both kernels rebuild identical prefix tables from `lengths`
// each call (no data-dependent cross-kernel handoff; R3/R10 lessons).
// rowstart[b] = sum of clamped lengths < b (global valid-row prefix).
// slotbase[b] = prefix of per-batch partial-slot counts, where batch b's
// slots are one per block j in [jlo_b, jhi_b] (blocks intersecting b's rows).
// Block row range: r in [ceil(W*j/G), ceil(W*(j+1)/G)).

// ---------------------------------------------------------------------------
// Kernel 1: exact-balanced partial max. Block j owns a contiguous range of
// the global valid-row list (quantum = 1 row = one D-vector). Flushes one
// partial slot per (batch, block) pair it touches.
// ---------------------------------------------------------------------------
__global__ __launch_bounds__(256, 4)
void feasel_rows_partial_kernel(const float* __restrict__ feat,
                                const int* __restrict__ lengths,
                                float* __restrict__ part,
                                int B, int L, int DV, int G) {
    __shared__ int rowstart[1025];       // B <= 1024
    __shared__ int slotbase[1025];
    const int t = threadIdx.x;
    const int j = blockIdx.x;

    if (t == 0) {
        rowstart[0] = 0;
        for (int b = 0; b < B; ++b) {
            int len = lengths[b];
            len = len < 0 ? 0 : (len > L ? L : len);
            rowstart[b + 1] = rowstart[b] + len;
        }
    }
    __syncthreads();
    const int W = rowstart[B];

    // per-batch slot counts (divisions parallelized across threads)
    for (int b = t; b < B; b += blockDim.x) {
        int s = 0;
        if (W > 0 && rowstart[b + 1] > rowstart[b]) {
            int jlo = (int)((unsigned long long)rowstart[b] * G / W);
            int jhi = (int)((unsigned long long)(rowstart[b + 1] - 1) * G / W);
            s = jhi - jlo + 1;
        }
        slotbase[b + 1] = s;
    }
    __syncthreads();
    if (t == 0) {
        slotbase[0] = 0;
        for (int b = 0; b < B; ++b) slotbase[b + 1] += slotbase[b];
    }
    __syncthreads();

    if (W == 0) return;
    const int r0 = (int)(((unsigned long long)W * j + G - 1) / G);
    int       r1 = (int)(((unsigned long long)W * (j + 1) + G - 1) / G);
    if (r1 > W) r1 = W;
    if (r0 >= r1) return;

    // containing batch for r0: largest b with rowstart[b] <= r0
    int lo = 0, hi = B;
    while (hi - lo > 1) {
        int m = (lo + hi) >> 1;
        if (rowstart[m] <= r0) lo = m; else hi = m;
    }
    int b = lo;
    int r = r0;

    while (r < r1) {
        while (rowstart[b + 1] <= r) ++b;          // skip empty batches
        const int rend  = min(r1, rowstart[b + 1]);
        const int nrows = rend - r;
        const int l     = r - rowstart[b];

        const f32x4* __restrict__ p =
            reinterpret_cast<const f32x4*>(feat) + ((size_t)b * L + l) * DV + t;

        f32x4 a0 = fillv4(), a1 = fillv4(), a2 = fillv4(), a3 = fillv4();
        f32x4 a4 = fillv4(), a5 = fillv4(), a6 = fillv4(), a7 = fillv4();

        int k = 0;
        for (; k + 16 <= nrows; k += 16) {
            f32x4 v0  = ntload(p +  0 * (size_t)DV);
            f32x4 v1  = ntload(p +  1 * (size_t)DV);
            f32x4 v2  = ntload(p +  2 * (size_t)DV);
            f32x4 v3  = ntload(p +  3 * (size_t)DV);
            f32x4 v4  = ntload(p +  4 * (size_t)DV);
            f32x4 v5  = ntload(p +  5 * (size_t)DV);
            f32x4 v6  = ntload(p +  6 * (size_t)DV);
            f32x4 v7  = ntload(p +  7 * (size_t)DV);
            f32x4 v8  = ntload(p +  8 * (size_t)DV);
            f32x4 v9  = ntload(p +  9 * (size_t)DV);
            f32x4 v10 = ntload(p + 10 * (size_t)DV);
            f32x4 v11 = ntload(p + 11 * (size_t)DV);
            f32x4 v12 = ntload(p + 12 * (size_t)DV);
            f32x4 v13 = ntload(p + 13 * (size_t)DV);
            f32x4 v14 = ntload(p + 14 * (size_t)DV);
            f32x4 v15 = ntload(p + 15 * (size_t)DV);
            a0 = vmax4(a0, vmax4(v0,  v8));
            a1 = vmax4(a1, vmax4(v1,  v9));
            a2 = vmax4(a2, vmax4(v2,  v10));
            a3 = vmax4(a3, vmax4(v3,  v11));
            a4 = vmax4(a4, vmax4(v4,  v12));
            a5 = vmax4(a5, vmax4(v5,  v13));
            a6 = vmax4(a6, vmax4(v6,  v14));
            a7 = vmax4(a7, vmax4(v7,  v15));
            p += 16 * (size_t)DV;
        }
        for (; k + 4 <= nrows; k += 4) {
            a0 = vmax4(a0, ntload(p + 0 * (size_t)DV));
            a1 = vmax4(a1, ntload(p + 1 * (size_t)DV));
            a2 = vmax4(a2, ntload(p + 2 * (size_t)DV));
            a3 = vmax4(a3, ntload(p + 3 * (size_t)DV));
            p += 4 * (size_t)DV;
        }
        for (; k < nrows; ++k) {
            a0 = vmax4(a0, ntload(p));
            p += DV;
        }
        a0 = vmax4(a0, a1);
        a2 = vmax4(a2, a3);
        a4 = vmax4(a4, a5);
        a6 = vmax4(a6, a7);
        a0 = vmax4(vmax4(a0, a2), vmax4(a4, a6));

        const int jlo  = (int)((unsigned long long)rowstart[b] * G / W);
        const int slot = slotbase[b] + (j - jlo);
        reinterpret_cast<f32x4*>(part)[(size_t)slot * DV + t] = a0;

        r = rend;
    }
}

// ---------------------------------------------------------------------------
// Kernel 2: per batch, reduce its (at most jhi-jlo+1) partial slots; len==0->0.
// Grid (B, ceil(DV/64)) x 64. Reads only slots kernel1 wrote this call
// (same formulas, same `lengths`). Empty-range blocks (possible when W < G)
// are skipped via the identical ceil arithmetic.
// ---------------------------------------------------------------------------
__global__ void feasel_rows_reduce_kernel(const float* __restrict__ part,
                                          const int* __restrict__ lengths,
                                          float* __restrict__ out,
                                          int B, int L, int DV, int G) {
    __shared__ int rowstart[1025];
    __shared__ int slotbase[1025];
    const int t = threadIdx.x;

    if (t == 0) {
        rowstart[0] = 0;
        for (int bb = 0; bb < B; ++bb) {
            int len = lengths[bb];
            len = len < 0 ? 0 : (len > L ? L : len);
            rowstart[bb + 1] = rowstart[bb] + len;
        }
    }
    __syncthreads();
    const int W = rowstart[B];
    for (int bb = t; bb < B; bb += blockDim.x) {
        int s = 0;
        if (W > 0 && rowstart[bb + 1] > rowstart[bb]) {
            int jlo = (int)((unsigned long long)rowstart[bb] * G / W);
            int jhi = (int)((unsigned long long)(rowstart[bb + 1] - 1) * G / W);
            s = jhi - jlo + 1;
        }
        slotbase[bb + 1] = s;
    }
    __syncthreads();
    if (t == 0) {
        slotbase[0] = 0;
        for (int bb = 0; bb < B; ++bb) slotbase[bb + 1] += slotbase[bb];
    }
    __syncthreads();

    const int b = blockIdx.x;
    const int c = blockIdx.y * 64 + t;
    if (c >= DV) return;

    const int rb0 = rowstart[b], rb1 = rowstart[b + 1];
    f32x4 acc;
    if (rb1 <= rb0) {
        f32x4 z = {0.f, 0.f, 0.f, 0.f};
        acc = z;
    } else {
        const int jlo = (int)((unsigned long long)rb0 * G / W);
        const int jhi = (int)((unsigned long long)(rb1 - 1) * G / W);
        acc = fillv4();
        for (int j = jlo; j <= jhi; ++j) {
            int br0 = (int)(((unsigned long long)W * j + G - 1) / G);
            int br1 = (int)(((unsigned long long)W * (j + 1) + G - 1) / G);
            if (br1 > W) br1 = W;
            const int is = br0 > rb0 ? br0 : rb0;
            const int ie = br1 < rb1 ? br1 : rb1;
            if (is < ie) {
                const int slot = slotbase[b] + (j - jlo);
                acc = vmax4(acc,
                    reinterpret_cast<const f32x4*>(part)[(size_t)slot * DV + c]);
            }
        }
    }
    reinterpret_cast<f32x4*>(out)[(size_t)b * DV + c] = acc;
}

// ---------------------------------------------------------------------------
// Fallback (tiny ws or B > 1024): one block per batch, direct reduction.
// ---------------------------------------------------------------------------
__global__ void feasel_direct_kernel(const float* __restrict__ feat,
                                     const int* __restrict__ lengths,
                                     float* __restrict__ out,
                                     int L, int DV) {
    const int b = blockIdx.x;
    const int t = threadIdx.x;
    int len = lengths[b];
    len = len < 0 ? 0 : (len > L ? L : len);

    const f32x4* __restrict__ p =
        reinterpret_cast<const f32x4*>(feat) + (size_t)b * L * DV + t;

    f32x4 a0 = fillv4(), a1 = fillv4(), a2 = fillv4(), a3 = fillv4();
    int l = 0;
    for (; l + 4 <= len; l += 4) {
        a0 = vmax4(a0, ntload(p + 0 * (size_t)DV));
        a1 = vmax4(a1, ntload(p + 1 * (size_t)DV));
        a2 = vmax4(a2, ntload(p + 2 * (size_t)DV));
        a3 = vmax4(a3, ntload(p + 3 * (size_t)DV));
        p += 4 * (size_t)DV;
    }
    for (; l < len; ++l) {
        a0 = vmax4(a0, ntload(p));
        p += DV;
    }
    a0 = vmax4(vmax4(a0, a1), vmax4(a2, a3));
    if (len <= 0) {
        f32x4 z = {0.f, 0.f, 0.f, 0.f};
        a0 = z;
    }
    reinterpret_cast<f32x4*>(out)[(size_t)b * DV + t] = a0;
}

extern "C" void kernel_launch(void* const* d_in, const int* in_sizes, int n_in,
                              void* d_out, int out_size, void* d_ws, size_t ws_size,
                              hipStream_t stream) {
    const float* feat    = (const float*)d_in[0];   // [B, L, D] fp32
    const int*   lengths = (const int*)d_in[1];     // [B] int32
    float*       out     = (float*)d_out;           // [B, D] fp32

    const int B  = in_sizes[1];
    const int D  = out_size / B;                    // 1024
    const int DV = D / 4;                           // 256 float4 per row
    const int L  = in_sizes[0] / (B * D);           // 4096
    const int G  = 1024;                            // kernel1 grid

    // Partial buffer: at most G + B slots of D floats.
    const size_t part_bytes = (size_t)(G + B) * D * sizeof(float);

    if (part_bytes <= ws_size && B <= 1024) {
        float* part = (float*)d_ws;

        feasel_rows_partial_kernel<<<G, 256, 0, stream>>>(feat, lengths, part,
                                                          B, L, DV, G);

        dim3 grid2(B, (DV + 63) / 64);
        feasel_rows_reduce_kernel<<<grid2, 64, 0, stream>>>(part, lengths, out,
                                                            B, L, DV, G);
    } else {
        feasel_direct_kernel<<<B, DV, 0, stream>>>(feat, lengths, out, L, DV);
    }
}